// Round 2
// baseline (166.633 us; speedup 1.0000x reference)
//
#include <hip/hip_runtime.h>
#include <math.h>

// Problem constants: BSZ=64, BEAM=8, VOCAB=50257, STEP=5
// R11: occupancy/shape rewrite of phase 1. R10 post-mortem: forcing 13-deep
// per-wave MLP (asm-pinned burst) was NEUTRAL -> the 61us rowtop is NOT
// per-wave-MLP-bound; it is CU-concurrency/shape-bound (2.9 B/cyc/CU
// effective, invariant to HBM-vs-L3 residence, VALUBusy 7%). The measured
// RMSNorm shape (rolling 16B/lane loads, 32 waves/CU, no phase bursts) hits
// ~8 B/cyc/CU on reads. This version adopts that shape:
//   - quarter-row blocks: grid (4,512) = 2048 blocks x 256 thr = 32 waves/CU
//     of work, 8 blocks/CU resident (LDS 8.5KB, VGPR<=64 via lb(256,8)).
//   - compile-time threshold TAU=2.3: stream + compare + rare LDS append
//     (E[cands]=71/quarter on N(0,1); P(<16) ~ 2e-11). No register
//     retention, no tournament, 2 barriers.
//   - exactness fallback (any input): per-thread max is kept during the
//     stream; if count<16 or >cap, tournament computes exact T (16th
//     largest thread-max), segment is re-read appending x>=T (bound
//     16 owners x 53 elems = 848 <= 1024). Never taken on bench data.
// Phase 2 unchanged except it now merges 4 sorted 16-lists (64 real keys,
// one 64-lane bitonic; previously 32 keys + 32 pads).
#define BSZ   64
#define BEAM  8
#define VOCAB 50257
#define NSTEP 5
#define K     16
#define DIV_RATE 0.5f
#define N4    (VOCAB / 4)        // 12564 float4s (+1 tail scalar)
#define NSEG  4
#define SEGQ  (N4 / NSEG)        // 3141 f4 per quarter-row (exact)
#define QITER 12                 // 12*256 = 3072 f4 via main loop
#define QREM  (SEGQ - QITER * 256) // 69: threads tid<69 load a 13th f4
#define TAU   2.3f               // P(N(0,1)>=2.3)=0.0107 -> ~71 cands/quarter
#define SBUF_CAP 1024            // >= fallback proof bound 16*53=848

typedef unsigned long long u64;
typedef unsigned u32;
typedef float f32x4 __attribute__((ext_vector_type(4)));

// order-preserving float<->uint (monotone for all non-NaN)
__device__ __forceinline__ u32 f2s(float f) {
    u32 u = __float_as_uint(f);
    return (u & 0x80000000u) ? ~u : (u | 0x80000000u);
}
__device__ __forceinline__ float s2f(u32 s) {
    u32 u = (s & 0x80000000u) ? (s ^ 0x80000000u) : ~s;
    return __uint_as_float(u);
}

// wave(64)-wide max of a u64 key (validated R1-R10)
__device__ __forceinline__ u64 wmax64(u64 k) {
#pragma unroll
    for (int off = 32; off > 0; off >>= 1) {
        u32 lo = __shfl_xor((u32)k, off, 64);
        u32 hi = __shfl_xor((u32)(k >> 32), off, 64);
        u64 o = ((u64)hi << 32) | lo;
        if (o > k) k = o;
    }
    return k;
}

#define BSTEPS(X)                                                            \
    X(2, 1)                                                                  \
    X(4, 2)  X(4, 1)                                                         \
    X(8, 4)  X(8, 2)  X(8, 1)                                                \
    X(16, 8) X(16, 4) X(16, 2) X(16, 1)                                      \
    X(32, 16) X(32, 8) X(32, 4) X(32, 2) X(32, 1)                            \
    X(64, 32) X(64, 16) X(64, 8) X(64, 4) X(64, 2) X(64, 1)

// u32 ascending bitonic sort across 64 lanes (validated R3-R10)
__device__ __forceinline__ u32 bitonic64_asc(u32 v, int lane) {
#define BS32(K_, J_)                                                         \
    {                                                                        \
        u32 o = __shfl_xor(v, (J_), 64);                                     \
        bool tmin = ((lane & (J_)) == 0) == ((lane & (K_)) == 0);            \
        v = tmin ? (v < o ? v : o) : (v > o ? v : o);                        \
    }
    BSTEPS(BS32)
#undef BS32
    return v;
}

// u64 ascending bitonic sort across 64 lanes (same network, 2 shfl/step)
__device__ __forceinline__ u64 bitonic64_asc_u64(u64 v, int lane) {
#define BS64(K_, J_)                                                         \
    {                                                                        \
        u32 lo = __shfl_xor((u32)v, (J_), 64);                               \
        u32 hi = __shfl_xor((u32)(v >> 32), (J_), 64);                       \
        u64 o = ((u64)hi << 32) | lo;                                        \
        bool tmin = ((lane & (J_)) == 0) == ((lane & (K_)) == 0);            \
        v = tmin ? (v < o ? v : o) : (v > o ? v : o);                        \
    }
    BSTEPS(BS64)
#undef BS64
    return v;
}

// Phase 1: one 256-thread block per quarter-row. Rolling stream (groups of
// 4 independent f32x4 loads), per-f4 max prefilter against TAU, rare
// atomic append of (value,idx) keys into LDS. Tail: wave 0 sorts the
// candidate list via chunked u64 bitonic, writes sorted top-16.
// key = f2s(value)<<32 | ~vocab_idx (bias deferred: uniform per row).
__global__ __launch_bounds__(256, 8) void rowtop(
    const float* __restrict__ lprobs, u64* __restrict__ segk)
{
    const int tid  = threadIdx.x;
    const int lane = tid & 63;
    const int wave = tid >> 6;       // 0..3
    const int seg  = blockIdx.x;     // 0..3
    const int row  = blockIdx.y;     // 0..511

    const f32x4* rp4  = (const f32x4*)(lprobs + (size_t)row * VOCAB);
    const f32x4* base = rp4 + seg * SEGQ + tid;

    __shared__ u64 sbuf[SBUF_CAP];
    __shared__ u32 smax[64];         // 4 waves x top-16 maxima (fallback)
    __shared__ u32 sT;
    __shared__ int scnt;
    if (tid == 0) scnt = 0;
    __syncthreads();

#define APPTH(xx, ei, TH)                                                    \
    if ((xx) >= (TH)) {                                                      \
        int p = atomicAdd(&scnt, 1);                                         \
        if (p < SBUF_CAP) sbuf[p] = ((u64)f2s(xx) << 32) | (u32)~(u32)(ei);  \
    }
#define PROC(vv, f, TH)                                                      \
    {                                                                        \
        float m4 = fmaxf(fmaxf((vv).x, (vv).y), fmaxf((vv).z, (vv).w));      \
        m = fmaxf(m, m4);                                                    \
        if (m4 >= (TH)) {                                                    \
            int b4 = 4 * (f);                                                \
            APPTH((vv).x, b4 + 0, TH) APPTH((vv).y, b4 + 1, TH)              \
            APPTH((vv).z, b4 + 2, TH) APPTH((vv).w, b4 + 3, TH)              \
        }                                                                    \
    }

    float m = -INFINITY;             // per-thread max (fallback threshold)
    // ---- main stream: 3 groups x 4 independent loads (rolling MLP=4) ----
#pragma unroll
    for (int g = 0; g < 3; ++g) {
        f32x4 v0 = base[g * 1024 + 0 * 256];
        f32x4 v1 = base[g * 1024 + 1 * 256];
        f32x4 v2 = base[g * 1024 + 2 * 256];
        f32x4 v3 = base[g * 1024 + 3 * 256];
        const int f0 = seg * SEGQ + g * 1024 + tid;
        PROC(v0, f0 + 0 * 256, TAU)
        PROC(v1, f0 + 1 * 256, TAU)
        PROC(v2, f0 + 2 * 256, TAU)
        PROC(v3, f0 + 3 * 256, TAU)
    }
    if (tid < QREM) {
        f32x4 vr = base[QITER * 256];
        PROC(vr, seg * SEGQ + QITER * 256 + tid, TAU)
    }
    if (seg == NSEG - 1 && tid == 0) {          // vocab tail element 50256
        float x = ((const float*)rp4)[VOCAB - 1];
        m = fmaxf(m, x);
        APPTH(x, VOCAB - 1, TAU)
    }
    __syncthreads();

    int n = scnt;
    if (n < K || n > SBUF_CAP) {
        // ---- exact fallback (unreachable on N(0,1) bench data) ----
        // T = exact 16th largest of 256 thread-maxima; candidates >= T are
        // bounded by 16 owners x <=53 elems = 848 <= SBUF_CAP.
        u32 vs = bitonic64_asc(f2s(m), lane);
        if (lane >= 48) smax[wave * 16 + (lane - 48)] = vs;
        __syncthreads();
        if (wave == 0) {
            u32 w = bitonic64_asc(smax[lane], lane);
            if (lane == 48) sT = w;
        }
        if (tid == 0) scnt = 0;
        __syncthreads();
        const float T = s2f(sT);
#pragma unroll
        for (int g = 0; g < 3; ++g) {
            f32x4 v0 = base[g * 1024 + 0 * 256];
            f32x4 v1 = base[g * 1024 + 1 * 256];
            f32x4 v2 = base[g * 1024 + 2 * 256];
            f32x4 v3 = base[g * 1024 + 3 * 256];
            const int f0 = seg * SEGQ + g * 1024 + tid;
            PROC(v0, f0 + 0 * 256, T)
            PROC(v1, f0 + 1 * 256, T)
            PROC(v2, f0 + 2 * 256, T)
            PROC(v3, f0 + 3 * 256, T)
        }
        if (tid < QREM) {
            f32x4 vr = base[QITER * 256];
            PROC(vr, seg * SEGQ + QITER * 256 + tid, T)
        }
        if (seg == NSEG - 1 && tid == 0) {
            float x = ((const float*)rp4)[VOCAB - 1];
            APPTH(x, VOCAB - 1, T)
        }
        __syncthreads();
        n = scnt > SBUF_CAP ? SBUF_CAP : scnt;
    }
#undef PROC
#undef APPTH

    // ---- wave 0: sorted top-16 of candidates via chunked u64 bitonic ----
    if (wave == 0) {
        u64 run = 0;
        for (int b0 = 0; b0 < n; b0 += 48) {
            u64 v = run;                          // lanes 48..63 keep top-16
            if (lane < 48) { int p = b0 + lane; v = (p < n) ? sbuf[p] : 0; }
            v = bitonic64_asc_u64(v, lane);
            run = (lane >= 48) ? v : 0;
        }
        if (lane >= 48) {                         // rank 0 = best
            int r = 63 - lane;
            segk[((size_t)row * NSEG + seg) * K + r] = run;
        }
    }
}

// Phase 2: block b, wave j: merge beam j's four sorted 16-lists (one u64
// bitonic over 64 real keys; rank = lane position), apply bias + sibling
// penalty, wave 0 runs the validated 128->16 extraction.
__global__ __launch_bounds__(512) void finalize(
    const u64* __restrict__ segk, const float* __restrict__ scores,
    const int* __restrict__ step_ptr, float* __restrict__ out)
{
    const int tid  = threadIdx.x;
    const int lane = tid & 63;
    const int j    = tid >> 6;       // beam 0..7
    const int b    = blockIdx.x;
    const int row  = b * BEAM + j;
    const int step = *step_ptr;

    __shared__ u64 fkey[BEAM * K];
    __shared__ int fvid[BEAM * K];

    // merged row top-16: sort 64 real keys (unique: disjoint vocab quarters)
    u64 v = segk[(size_t)row * (NSEG * K) + lane];
    v = bitonic64_asc_u64(v, lane);
    // lanes 48..63 hold the row top-16 ascending; rank r = 63 - lane

    float* out_s = out;
    float* out_i = out + BSZ * K;
    float* out_b = out + 2 * BSZ * K;

    if (step == 0) {
        // reference: top_k(lprobs[:,0,:]): idx%vocab=idx, idx//vocab=0
        if (j == 0 && lane >= 48) {
            int r = 63 - lane;
            out_s[b * K + r] = s2f((u32)(v >> 32));
            out_i[b * K + r] = (float)(int)~(u32)v;
            out_b[b * K + r] = 0.0f;
        }
        return;
    }

    if (lane >= 48) {
        int r = 63 - lane;
        float val = s2f((u32)(v >> 32));
        float add = scores[row * NSTEP + step - 1];
        float sc  = val + add - (float)(r + 1) * DIV_RATE;
        int c = j * K + r;
        fkey[c] = ((u64)f2s(sc) << 32) | (u32)(127 - c);  // lower c wins ties
        fvid[c] = (int)~(u32)v;
    }
    __syncthreads();

    if (tid < 64) {
        u64 pa = fkey[lane];
        u64 pb = fkey[lane + 64];
        u64 m2 = 0;
#pragma unroll 1
        for (int it = 0; it < K; ++it) {
            u64 mm = wmax64(pa > pb ? pa : pb);
            if (lane == it) m2 = mm;
            if (pa == mm) pa = 0; else if (pb == mm) pb = 0;
        }
        if (lane < K) {
            int c = 127 - (int)(m2 & 0xFFFFFFFFull);
            out_s[b * K + lane] = s2f((u32)(m2 >> 32));
            out_i[b * K + lane] = (float)fvid[c];
            out_b[b * K + lane] = (float)(c >> 4);
        }
    }
}

extern "C" void kernel_launch(void* const* d_in, const int* in_sizes, int n_in,
                              void* d_out, int out_size, void* d_ws, size_t ws_size,
                              hipStream_t stream) {
    const float* lprobs = (const float*)d_in[0];
    const float* scores = (const float*)d_in[1];
    const int*   step   = (const int*)d_in[2];

    u64* segk = (u64*)d_ws;   // 512 rows * 4 segs * 16 keys * 8 B = 256 KB

    dim3 g1(NSEG, BSZ * BEAM);
    rowtop<<<g1, 256, 0, stream>>>(lprobs, segk);
    finalize<<<BSZ, 512, 0, stream>>>(segk, scores, step, (float*)d_out);
}

// Round 4
// 166.266 us; speedup vs baseline: 1.0022x; 1.0022x over previous
//
#include <hip/hip_runtime.h>
#include <math.h>

// Problem constants: BSZ=64, BEAM=8, VOCAB=50257, STEP=5
// R13 = R12 resubmitted verbatim (R12's bench died on container acquisition
// — infra flake, no compile error, no profile; OOB/LDS/workspace re-audited
// clean). Theory under test: ALIGNMENT. R10 (forced MLP) and R11
// (32 waves/CU rolling stream) were both neutral; the standing invariant is
// that every rowtop reads via (float4*)(lprobs + row*VOCAB) and
// VOCAB=50257 => row r's base byte = 4*(r%4) (mod 16): 75% of rows issue
// 16B-MISALIGNED dwordx4 loads, which HW splits into multiple aligned
// transactions => ~3-4x request rate => the observed 1.69 TB/s cap that is
// invariant to shape/occupancy/MLP/data residence (fill hits 6.7 TB/s,
// aligned RMSNorm reference 4.9 TB/s, same 16B/lane width).
// Fix: peel head = (4 - row%4) % 4 scalar floats so the f32x4 bulk pointer
// is truly 16B-aligned; peel <=3 tail scalars; stream the aligned middle
// exactly as R11 (TAU prefilter + LDS append + chunked bitonic top-16;
// exact-T tournament fallback for adversarial inputs, bound 880 <= 1024).
// Segment boundaries shift by <=3 elements; phase 2 merges any 4-way row
// partition, so semantics are unchanged.
#define BSZ   64
#define BEAM  8
#define VOCAB 50257
#define NSTEP 5
#define K     16
#define DIV_RATE 0.5f
#define NSEG  4
#define SEGF4 3141               // f4 per segment (segs 0..2; seg 3: nf4-9423)
#define QITER 12                 // 12*256 = 3072 f4 unconditional per seg
#define TAU   2.3f               // P(N(0,1)>=2.3)=0.0107 -> ~134 cands/seg
#define SBUF_CAP 1024            // >= fallback proof bound 16*55=880

typedef unsigned long long u64;
typedef unsigned u32;
typedef float f32x4 __attribute__((ext_vector_type(4)));

// order-preserving float<->uint (monotone for all non-NaN)
__device__ __forceinline__ u32 f2s(float f) {
    u32 u = __float_as_uint(f);
    return (u & 0x80000000u) ? ~u : (u | 0x80000000u);
}
__device__ __forceinline__ float s2f(u32 s) {
    u32 u = (s & 0x80000000u) ? (s ^ 0x80000000u) : ~s;
    return __uint_as_float(u);
}

// wave(64)-wide max of a u64 key (validated R1-R12)
__device__ __forceinline__ u64 wmax64(u64 k) {
#pragma unroll
    for (int off = 32; off > 0; off >>= 1) {
        u32 lo = __shfl_xor((u32)k, off, 64);
        u32 hi = __shfl_xor((u32)(k >> 32), off, 64);
        u64 o = ((u64)hi << 32) | lo;
        if (o > k) k = o;
    }
    return k;
}

#define BSTEPS(X)                                                            \
    X(2, 1)                                                                  \
    X(4, 2)  X(4, 1)                                                         \
    X(8, 4)  X(8, 2)  X(8, 1)                                                \
    X(16, 8) X(16, 4) X(16, 2) X(16, 1)                                      \
    X(32, 16) X(32, 8) X(32, 4) X(32, 2) X(32, 1)                            \
    X(64, 32) X(64, 16) X(64, 8) X(64, 4) X(64, 2) X(64, 1)

// u32 ascending bitonic sort across 64 lanes (validated R3-R12)
__device__ __forceinline__ u32 bitonic64_asc(u32 v, int lane) {
#define BS32(K_, J_)                                                         \
    {                                                                        \
        u32 o = __shfl_xor(v, (J_), 64);                                     \
        bool tmin = ((lane & (J_)) == 0) == ((lane & (K_)) == 0);            \
        v = tmin ? (v < o ? v : o) : (v > o ? v : o);                        \
    }
    BSTEPS(BS32)
#undef BS32
    return v;
}

// u64 ascending bitonic sort across 64 lanes (same network, 2 shfl/step)
__device__ __forceinline__ u64 bitonic64_asc_u64(u64 v, int lane) {
#define BS64(K_, J_)                                                         \
    {                                                                        \
        u32 lo = __shfl_xor((u32)v, (J_), 64);                               \
        u32 hi = __shfl_xor((u32)(v >> 32), (J_), 64);                       \
        u64 o = ((u64)hi << 32) | lo;                                        \
        bool tmin = ((lane & (J_)) == 0) == ((lane & (K_)) == 0);            \
        v = tmin ? (v < o ? v : o) : (v > o ? v : o);                        \
    }
    BSTEPS(BS64)
#undef BS64
    return v;
}

// Phase 1: one 256-thread block per (row, quarter). Aligned rolling stream
// (3 groups x 4 independent 16B-ALIGNED f32x4 loads), per-f4 TAU prefilter,
// rare atomic append of (value,idx) keys into LDS. Head/tail scalars of the
// row handled by tid 0 of seg 0 / seg 3. Tail: wave 0 sorts candidates via
// chunked u64 bitonic, writes sorted top-16.
// key = f2s(value)<<32 | ~vocab_idx (bias deferred: uniform per row).
__global__ __launch_bounds__(256, 8) void rowtop(
    const float* __restrict__ lprobs, u64* __restrict__ segk)
{
    const int tid  = threadIdx.x;
    const int lane = tid & 63;
    const int wave = tid >> 6;       // 0..3
    const int seg  = blockIdx.x;     // 0..3
    const int row  = blockIdx.y;     // 0..511

    const int head = (4 - (row & 3)) & 3;       // scalars before aligned bulk
    const int nf4  = (VOCAB - head) >> 2;       // 12563 or 12564
    const int tail = VOCAB - head - 4 * nf4;    // 0..3 scalars after bulk

    const float* rowp = lprobs + (size_t)row * VOCAB;
    const f32x4* rp4  = (const f32x4*)(rowp + head);   // truly 16B-aligned
    const int segBase = seg * SEGF4;
    const int segCnt  = (seg < NSEG - 1) ? SEGF4 : (nf4 - (NSEG - 1) * SEGF4);
    const f32x4* base = rp4 + segBase + tid;

    __shared__ u64 sbuf[SBUF_CAP];
    __shared__ u32 smax[64];         // 4 waves x top-16 maxima (fallback)
    __shared__ u32 sT;
    __shared__ int scnt;
    if (tid == 0) scnt = 0;
    __syncthreads();

#define APPTH(xx, ei, TH)                                                    \
    if ((xx) >= (TH)) {                                                      \
        int p = atomicAdd(&scnt, 1);                                         \
        if (p < SBUF_CAP) sbuf[p] = ((u64)f2s(xx) << 32) | (u32)~(u32)(ei);  \
    }
#define PROC(vv, f, TH)                                                      \
    {                                                                        \
        float m4 = fmaxf(fmaxf((vv).x, (vv).y), fmaxf((vv).z, (vv).w));      \
        m = fmaxf(m, m4);                                                    \
        if (m4 >= (TH)) {                                                    \
            int b4 = head + 4 * (f);                                         \
            APPTH((vv).x, b4 + 0, TH) APPTH((vv).y, b4 + 1, TH)              \
            APPTH((vv).z, b4 + 2, TH) APPTH((vv).w, b4 + 3, TH)              \
        }                                                                    \
    }
// row-edge scalars (dword-aligned loads; counts <= 3 each)
#define EDGES(TH)                                                            \
    if (seg == 0 && tid == 0) {                                              \
        for (int h = 0; h < head; ++h) {                                     \
            float x = rowp[h];                                               \
            m = fmaxf(m, x);                                                 \
            APPTH(x, h, TH)                                                  \
        }                                                                    \
    }                                                                        \
    if (seg == NSEG - 1 && tid == 0) {                                       \
        for (int t = 0; t < tail; ++t) {                                     \
            int ei = head + 4 * nf4 + t;                                     \
            float x = rowp[ei];                                              \
            m = fmaxf(m, x);                                                 \
            APPTH(x, ei, TH)                                                 \
        }                                                                    \
    }

    float m = -INFINITY;             // per-thread max (fallback threshold)
    const int rem = segCnt - QITER * 256;   // 68 or 69
    // ---- main stream: 3 groups x 4 independent aligned loads ----
#pragma unroll
    for (int g = 0; g < 3; ++g) {
        f32x4 v0 = base[g * 1024 + 0 * 256];
        f32x4 v1 = base[g * 1024 + 1 * 256];
        f32x4 v2 = base[g * 1024 + 2 * 256];
        f32x4 v3 = base[g * 1024 + 3 * 256];
        const int f0 = segBase + g * 1024 + tid;
        PROC(v0, f0 + 0 * 256, TAU)
        PROC(v1, f0 + 1 * 256, TAU)
        PROC(v2, f0 + 2 * 256, TAU)
        PROC(v3, f0 + 3 * 256, TAU)
    }
    if (tid < rem) {
        f32x4 vr = base[QITER * 256];
        PROC(vr, segBase + QITER * 256 + tid, TAU)
    }
    EDGES(TAU)
    __syncthreads();

    int n = scnt;
    if (n < K || n > SBUF_CAP) {
        // ---- exact fallback (unreachable on N(0,1) bench data) ----
        // T = exact 16th largest of 256 thread-maxima; candidates >= T are
        // bounded by 16 owners x <=55 elems = 880 <= SBUF_CAP.
        u32 vs = bitonic64_asc(f2s(m), lane);
        if (lane >= 48) smax[wave * 16 + (lane - 48)] = vs;
        __syncthreads();
        if (wave == 0) {
            u32 w = bitonic64_asc(smax[lane], lane);
            if (lane == 48) sT = w;
        }
        if (tid == 0) scnt = 0;
        __syncthreads();
        const float T = s2f(sT);
#pragma unroll
        for (int g = 0; g < 3; ++g) {
            f32x4 v0 = base[g * 1024 + 0 * 256];
            f32x4 v1 = base[g * 1024 + 1 * 256];
            f32x4 v2 = base[g * 1024 + 2 * 256];
            f32x4 v3 = base[g * 1024 + 3 * 256];
            const int f0 = segBase + g * 1024 + tid;
            PROC(v0, f0 + 0 * 256, T)
            PROC(v1, f0 + 1 * 256, T)
            PROC(v2, f0 + 2 * 256, T)
            PROC(v3, f0 + 3 * 256, T)
        }
        if (tid < rem) {
            f32x4 vr = base[QITER * 256];
            PROC(vr, segBase + QITER * 256 + tid, T)
        }
        EDGES(T)
        __syncthreads();
        n = scnt > SBUF_CAP ? SBUF_CAP : scnt;
    }
#undef EDGES
#undef PROC
#undef APPTH

    // ---- wave 0: sorted top-16 of candidates via chunked u64 bitonic ----
    if (wave == 0) {
        u64 run = 0;
        for (int b0 = 0; b0 < n; b0 += 48) {
            u64 v = run;                          // lanes 48..63 keep top-16
            if (lane < 48) { int p = b0 + lane; v = (p < n) ? sbuf[p] : 0; }
            v = bitonic64_asc_u64(v, lane);
            run = (lane >= 48) ? v : 0;
        }
        if (lane >= 48) {                         // rank 0 = best
            int r = 63 - lane;
            segk[((size_t)row * NSEG + seg) * K + r] = run;
        }
    }
}

// Phase 2: block b, wave j: merge beam j's four sorted 16-lists (one u64
// bitonic over 64 real keys; rank = lane position), apply bias + sibling
// penalty, wave 0 runs the validated 128->16 extraction.
__global__ __launch_bounds__(512) void finalize(
    const u64* __restrict__ segk, const float* __restrict__ scores,
    const int* __restrict__ step_ptr, float* __restrict__ out)
{
    const int tid  = threadIdx.x;
    const int lane = tid & 63;
    const int j    = tid >> 6;       // beam 0..7
    const int b    = blockIdx.x;
    const int row  = b * BEAM + j;
    const int step = *step_ptr;

    __shared__ u64 fkey[BEAM * K];
    __shared__ int fvid[BEAM * K];

    // merged row top-16: sort 64 real keys (unique: disjoint vocab ranges)
    u64 v = segk[(size_t)row * (NSEG * K) + lane];
    v = bitonic64_asc_u64(v, lane);
    // lanes 48..63 hold the row top-16 ascending; rank r = 63 - lane

    float* out_s = out;
    float* out_i = out + BSZ * K;
    float* out_b = out + 2 * BSZ * K;

    if (step == 0) {
        // reference: top_k(lprobs[:,0,:]): idx%vocab=idx, idx//vocab=0
        if (j == 0 && lane >= 48) {
            int r = 63 - lane;
            out_s[b * K + r] = s2f((u32)(v >> 32));
            out_i[b * K + r] = (float)(int)~(u32)v;
            out_b[b * K + r] = 0.0f;
        }
        return;
    }

    if (lane >= 48) {
        int r = 63 - lane;
        float val = s2f((u32)(v >> 32));
        float add = scores[row * NSTEP + step - 1];
        float sc  = val + add - (float)(r + 1) * DIV_RATE;
        int c = j * K + r;
        fkey[c] = ((u64)f2s(sc) << 32) | (u32)(127 - c);  // lower c wins ties
        fvid[c] = (int)~(u32)v;
    }
    __syncthreads();

    if (tid < 64) {
        u64 pa = fkey[lane];
        u64 pb = fkey[lane + 64];
        u64 m2 = 0;
#pragma unroll 1
        for (int it = 0; it < K; ++it) {
            u64 mm = wmax64(pa > pb ? pa : pb);
            if (lane == it) m2 = mm;
            if (pa == mm) pa = 0; else if (pb == mm) pb = 0;
        }
        if (lane < K) {
            int c = 127 - (int)(m2 & 0xFFFFFFFFull);
            out_s[b * K + lane] = s2f((u32)(m2 >> 32));
            out_i[b * K + lane] = (float)fvid[c];
            out_b[b * K + lane] = (float)(c >> 4);
        }
    }
}

extern "C" void kernel_launch(void* const* d_in, const int* in_sizes, int n_in,
                              void* d_out, int out_size, void* d_ws, size_t ws_size,
                              hipStream_t stream) {
    const float* lprobs = (const float*)d_in[0];
    const float* scores = (const float*)d_in[1];
    const int*   step   = (const int*)d_in[2];

    u64* segk = (u64*)d_ws;   // 512 rows * 4 segs * 16 keys * 8 B = 256 KB

    dim3 g1(NSEG, BSZ * BEAM);
    rowtop<<<g1, 256, 0, stream>>>(lprobs, segk);
    finalize<<<BSZ, 512, 0, stream>>>(segk, scores, step, (float*)d_out);
}

// Round 5
// 156.457 us; speedup vs baseline: 1.0650x; 1.0627x over previous
//
#include <hip/hip_runtime.h>
#include <math.h>

// Problem constants: BSZ=64, BEAM=8, VOCAB=50257, STEP=5
// R14: NON-TEMPORAL loads. Falsified so far: per-wave MLP (R10, asm-pinned
// 13-deep burst: neutral), occupancy/shape (R11, 32 waves/CU rolling
// stream: neutral), 16B alignment (R13, head/tail peel: neutral). rowtop is
// pinned at ~61 us = 2.9 B/cyc/CU across all variants, invariant to data
// residence (R0 half-cold instance identical), with rocprof-serialized solo
// timestamps — so no concurrency artifact. Chip arithmetic: 1.61M lines /
// 146K cyc / 8 XCDs ~= 1.4 lines/cyc/XCD -> shared per-XCD limit on the
// L2 MISS/ALLOCATE path (12.9 MB/XCD streamed through a 4 MB L2, every
// line allocate+evict; L3-hit and HBM fills share that path => residence
// invariance; the 6.7 TB/s fill is no-allocate streaming WRITES).
// Probe: __builtin_nontemporal_load on the bulk stream (global_load_dwordx4
// nt) bypasses L2 allocation. If the theory holds, rowtop 61 -> ~20-30 us.
// If neutral, all in-kernel levers are exhausted -> declare roofline.
// Everything else identical to R13 (aligned peel + TAU prefilter + LDS
// append + chunked bitonic top-16; exact-T tournament fallback with plain
// loads, unreachable on N(0,1) bench data).
#define BSZ   64
#define BEAM  8
#define VOCAB 50257
#define NSTEP 5
#define K     16
#define DIV_RATE 0.5f
#define NSEG  4
#define SEGF4 3141               // f4 per segment (segs 0..2; seg 3: nf4-9423)
#define QITER 12                 // 12*256 = 3072 f4 unconditional per seg
#define TAU   2.3f               // P(N(0,1)>=2.3)=0.0107 -> ~134 cands/seg
#define SBUF_CAP 1024            // >= fallback proof bound 16*55=880

typedef unsigned long long u64;
typedef unsigned u32;
typedef float f32x4 __attribute__((ext_vector_type(4)));

// order-preserving float<->uint (monotone for all non-NaN)
__device__ __forceinline__ u32 f2s(float f) {
    u32 u = __float_as_uint(f);
    return (u & 0x80000000u) ? ~u : (u | 0x80000000u);
}
__device__ __forceinline__ float s2f(u32 s) {
    u32 u = (s & 0x80000000u) ? (s ^ 0x80000000u) : ~s;
    return __uint_as_float(u);
}

// non-temporal 16B load: global_load_dwordx4 with nt (bypass L2 allocate)
__device__ __forceinline__ f32x4 ntload(const f32x4* p) {
    return __builtin_nontemporal_load(p);
}

// wave(64)-wide max of a u64 key (validated R1-R13)
__device__ __forceinline__ u64 wmax64(u64 k) {
#pragma unroll
    for (int off = 32; off > 0; off >>= 1) {
        u32 lo = __shfl_xor((u32)k, off, 64);
        u32 hi = __shfl_xor((u32)(k >> 32), off, 64);
        u64 o = ((u64)hi << 32) | lo;
        if (o > k) k = o;
    }
    return k;
}

#define BSTEPS(X)                                                            \
    X(2, 1)                                                                  \
    X(4, 2)  X(4, 1)                                                         \
    X(8, 4)  X(8, 2)  X(8, 1)                                                \
    X(16, 8) X(16, 4) X(16, 2) X(16, 1)                                      \
    X(32, 16) X(32, 8) X(32, 4) X(32, 2) X(32, 1)                            \
    X(64, 32) X(64, 16) X(64, 8) X(64, 4) X(64, 2) X(64, 1)

// u32 ascending bitonic sort across 64 lanes (validated R3-R13)
__device__ __forceinline__ u32 bitonic64_asc(u32 v, int lane) {
#define BS32(K_, J_)                                                         \
    {                                                                        \
        u32 o = __shfl_xor(v, (J_), 64);                                     \
        bool tmin = ((lane & (J_)) == 0) == ((lane & (K_)) == 0);            \
        v = tmin ? (v < o ? v : o) : (v > o ? v : o);                        \
    }
    BSTEPS(BS32)
#undef BS32
    return v;
}

// u64 ascending bitonic sort across 64 lanes (same network, 2 shfl/step)
__device__ __forceinline__ u64 bitonic64_asc_u64(u64 v, int lane) {
#define BS64(K_, J_)                                                         \
    {                                                                        \
        u32 lo = __shfl_xor((u32)v, (J_), 64);                               \
        u32 hi = __shfl_xor((u32)(v >> 32), (J_), 64);                       \
        u64 o = ((u64)hi << 32) | lo;                                        \
        bool tmin = ((lane & (J_)) == 0) == ((lane & (K_)) == 0);            \
        v = tmin ? (v < o ? v : o) : (v > o ? v : o);                        \
    }
    BSTEPS(BS64)
#undef BS64
    return v;
}

// Phase 1: one 256-thread block per (row, quarter). Aligned rolling stream
// (3 groups x 4 independent 16B-ALIGNED NT f32x4 loads), per-f4 TAU
// prefilter, rare atomic append of (value,idx) keys into LDS. Head/tail
// scalars of the row handled by tid 0 of seg 0 / seg 3. Tail: wave 0 sorts
// candidates via chunked u64 bitonic, writes sorted top-16.
// key = f2s(value)<<32 | ~vocab_idx (bias deferred: uniform per row).
__global__ __launch_bounds__(256, 8) void rowtop(
    const float* __restrict__ lprobs, u64* __restrict__ segk)
{
    const int tid  = threadIdx.x;
    const int lane = tid & 63;
    const int wave = tid >> 6;       // 0..3
    const int seg  = blockIdx.x;     // 0..3
    const int row  = blockIdx.y;     // 0..511

    const int head = (4 - (row & 3)) & 3;       // scalars before aligned bulk
    const int nf4  = (VOCAB - head) >> 2;       // 12563 or 12564
    const int tail = VOCAB - head - 4 * nf4;    // 0..3 scalars after bulk

    const float* rowp = lprobs + (size_t)row * VOCAB;
    const f32x4* rp4  = (const f32x4*)(rowp + head);   // truly 16B-aligned
    const int segBase = seg * SEGF4;
    const int segCnt  = (seg < NSEG - 1) ? SEGF4 : (nf4 - (NSEG - 1) * SEGF4);
    const f32x4* base = rp4 + segBase + tid;

    __shared__ u64 sbuf[SBUF_CAP];
    __shared__ u32 smax[64];         // 4 waves x top-16 maxima (fallback)
    __shared__ u32 sT;
    __shared__ int scnt;
    if (tid == 0) scnt = 0;
    __syncthreads();

#define APPTH(xx, ei, TH)                                                    \
    if ((xx) >= (TH)) {                                                      \
        int p = atomicAdd(&scnt, 1);                                         \
        if (p < SBUF_CAP) sbuf[p] = ((u64)f2s(xx) << 32) | (u32)~(u32)(ei);  \
    }
#define PROC(vv, f, TH)                                                      \
    {                                                                        \
        float m4 = fmaxf(fmaxf((vv).x, (vv).y), fmaxf((vv).z, (vv).w));      \
        m = fmaxf(m, m4);                                                    \
        if (m4 >= (TH)) {                                                    \
            int b4 = head + 4 * (f);                                         \
            APPTH((vv).x, b4 + 0, TH) APPTH((vv).y, b4 + 1, TH)              \
            APPTH((vv).z, b4 + 2, TH) APPTH((vv).w, b4 + 3, TH)              \
        }                                                                    \
    }
// row-edge scalars (dword-aligned loads; counts <= 3 each)
#define EDGES(TH)                                                            \
    if (seg == 0 && tid == 0) {                                              \
        for (int h = 0; h < head; ++h) {                                     \
            float x = rowp[h];                                               \
            m = fmaxf(m, x);                                                 \
            APPTH(x, h, TH)                                                  \
        }                                                                    \
    }                                                                        \
    if (seg == NSEG - 1 && tid == 0) {                                       \
        for (int t = 0; t < tail; ++t) {                                     \
            int ei = head + 4 * nf4 + t;                                     \
            float x = rowp[ei];                                              \
            m = fmaxf(m, x);                                                 \
            APPTH(x, ei, TH)                                                 \
        }                                                                    \
    }

    float m = -INFINITY;             // per-thread max (fallback threshold)
    const int rem = segCnt - QITER * 256;   // 68 or 69
    // ---- main stream: 3 groups x 4 independent aligned NT loads ----
#pragma unroll
    for (int g = 0; g < 3; ++g) {
        f32x4 v0 = ntload(base + g * 1024 + 0 * 256);
        f32x4 v1 = ntload(base + g * 1024 + 1 * 256);
        f32x4 v2 = ntload(base + g * 1024 + 2 * 256);
        f32x4 v3 = ntload(base + g * 1024 + 3 * 256);
        const int f0 = segBase + g * 1024 + tid;
        PROC(v0, f0 + 0 * 256, TAU)
        PROC(v1, f0 + 1 * 256, TAU)
        PROC(v2, f0 + 2 * 256, TAU)
        PROC(v3, f0 + 3 * 256, TAU)
    }
    if (tid < rem) {
        f32x4 vr = ntload(base + QITER * 256);
        PROC(vr, segBase + QITER * 256 + tid, TAU)
    }
    EDGES(TAU)
    __syncthreads();

    int n = scnt;
    if (n < K || n > SBUF_CAP) {
        // ---- exact fallback (unreachable on N(0,1) bench data) ----
        // T = exact 16th largest of 256 thread-maxima; candidates >= T are
        // bounded by 16 owners x <=55 elems = 880 <= SBUF_CAP.
        u32 vs = bitonic64_asc(f2s(m), lane);
        if (lane >= 48) smax[wave * 16 + (lane - 48)] = vs;
        __syncthreads();
        if (wave == 0) {
            u32 w = bitonic64_asc(smax[lane], lane);
            if (lane == 48) sT = w;
        }
        if (tid == 0) scnt = 0;
        __syncthreads();
        const float T = s2f(sT);
#pragma unroll
        for (int g = 0; g < 3; ++g) {
            f32x4 v0 = base[g * 1024 + 0 * 256];
            f32x4 v1 = base[g * 1024 + 1 * 256];
            f32x4 v2 = base[g * 1024 + 2 * 256];
            f32x4 v3 = base[g * 1024 + 3 * 256];
            const int f0 = segBase + g * 1024 + tid;
            PROC(v0, f0 + 0 * 256, T)
            PROC(v1, f0 + 1 * 256, T)
            PROC(v2, f0 + 2 * 256, T)
            PROC(v3, f0 + 3 * 256, T)
        }
        if (tid < rem) {
            f32x4 vr = base[QITER * 256];
            PROC(vr, segBase + QITER * 256 + tid, T)
        }
        EDGES(T)
        __syncthreads();
        n = scnt > SBUF_CAP ? SBUF_CAP : scnt;
    }
#undef EDGES
#undef PROC
#undef APPTH

    // ---- wave 0: sorted top-16 of candidates via chunked u64 bitonic ----
    if (wave == 0) {
        u64 run = 0;
        for (int b0 = 0; b0 < n; b0 += 48) {
            u64 v = run;                          // lanes 48..63 keep top-16
            if (lane < 48) { int p = b0 + lane; v = (p < n) ? sbuf[p] : 0; }
            v = bitonic64_asc_u64(v, lane);
            run = (lane >= 48) ? v : 0;
        }
        if (lane >= 48) {                         // rank 0 = best
            int r = 63 - lane;
            segk[((size_t)row * NSEG + seg) * K + r] = run;
        }
    }
}

// Phase 2: block b, wave j: merge beam j's four sorted 16-lists (one u64
// bitonic over 64 real keys; rank = lane position), apply bias + sibling
// penalty, wave 0 runs the validated 128->16 extraction.
__global__ __launch_bounds__(512) void finalize(
    const u64* __restrict__ segk, const float* __restrict__ scores,
    const int* __restrict__ step_ptr, float* __restrict__ out)
{
    const int tid  = threadIdx.x;
    const int lane = tid & 63;
    const int j    = tid >> 6;       // beam 0..7
    const int b    = blockIdx.x;
    const int row  = b * BEAM + j;
    const int step = *step_ptr;

    __shared__ u64 fkey[BEAM * K];
    __shared__ int fvid[BEAM * K];

    // merged row top-16: sort 64 real keys (unique: disjoint vocab ranges)
    u64 v = segk[(size_t)row * (NSEG * K) + lane];
    v = bitonic64_asc_u64(v, lane);
    // lanes 48..63 hold the row top-16 ascending; rank r = 63 - lane

    float* out_s = out;
    float* out_i = out + BSZ * K;
    float* out_b = out + 2 * BSZ * K;

    if (step == 0) {
        // reference: top_k(lprobs[:,0,:]): idx%vocab=idx, idx//vocab=0
        if (j == 0 && lane >= 48) {
            int r = 63 - lane;
            out_s[b * K + r] = s2f((u32)(v >> 32));
            out_i[b * K + r] = (float)(int)~(u32)v;
            out_b[b * K + r] = 0.0f;
        }
        return;
    }

    if (lane >= 48) {
        int r = 63 - lane;
        float val = s2f((u32)(v >> 32));
        float add = scores[row * NSTEP + step - 1];
        float sc  = val + add - (float)(r + 1) * DIV_RATE;
        int c = j * K + r;
        fkey[c] = ((u64)f2s(sc) << 32) | (u32)(127 - c);  // lower c wins ties
        fvid[c] = (int)~(u32)v;
    }
    __syncthreads();

    if (tid < 64) {
        u64 pa = fkey[lane];
        u64 pb = fkey[lane + 64];
        u64 m2 = 0;
#pragma unroll 1
        for (int it = 0; it < K; ++it) {
            u64 mm = wmax64(pa > pb ? pa : pb);
            if (lane == it) m2 = mm;
            if (pa == mm) pa = 0; else if (pb == mm) pb = 0;
        }
        if (lane < K) {
            int c = 127 - (int)(m2 & 0xFFFFFFFFull);
            out_s[b * K + lane] = s2f((u32)(m2 >> 32));
            out_i[b * K + lane] = (float)fvid[c];
            out_b[b * K + lane] = (float)(c >> 4);
        }
    }
}

extern "C" void kernel_launch(void* const* d_in, const int* in_sizes, int n_in,
                              void* d_out, int out_size, void* d_ws, size_t ws_size,
                              hipStream_t stream) {
    const float* lprobs = (const float*)d_in[0];
    const float* scores = (const float*)d_in[1];
    const int*   step   = (const int*)d_in[2];

    u64* segk = (u64*)d_ws;   // 512 rows * 4 segs * 16 keys * 8 B = 256 KB

    dim3 g1(NSEG, BSZ * BEAM);
    rowtop<<<g1, 256, 0, stream>>>(lprobs, segk);
    finalize<<<BSZ, 512, 0, stream>>>(segk, scores, step, (float*)d_out);
}